// Round 11
// baseline (6713.778 us; speedup 1.0000x reference)
//
#include <hip/hip_runtime.h>
#include <hip/hip_bf16.h>

#define B_  256
#define T_  1024
#define D_  256
#define H_  512
#define G_  2048   // 4*H
#define KT_ 768    // H + D

// ws layout (bytes)
#define WPACK_OFF 0                        // 2048*768*2 = 3145728
#define BIAS_OFF  3145728                  // 2048*4     = 8192
#define H0_OFF    (BIAS_OFF + 8192)        // 256*512*2  = 262144
#define H1_OFF    (H0_OFF + 262144)
#define C_OFF     (H1_OFF + 262144)        // 512KB: fallback cbuf
#define FLAG_OFF  C_OFF                    // flags alias cbuf (paths are exclusive):
                                           // 512 flags x 32 uints = 64KB

typedef __attribute__((ext_vector_type(8))) short bf16x8;
typedef __attribute__((ext_vector_type(4))) float f32x4;

__device__ __forceinline__ unsigned short f2bf(float f) {
    unsigned int u = __float_as_uint(f);
    u = (u + 0x7fffu + ((u >> 16) & 1u)) >> 16;   // RNE
    return (unsigned short)u;
}
__device__ __forceinline__ float bf2f(unsigned short s) {
    return __uint_as_float(((unsigned int)s) << 16);
}
__device__ __forceinline__ float sigm(float v) { return 1.0f / (1.0f + __expf(-v)); }
__device__ __forceinline__ float tanh_(float v) { return 2.0f / (1.0f + __expf(-2.0f * v)) - 1.0f; }

// ---- prep: pack [W_hh | W_ih] rows into bf16 Wpack[2048][768] ----
__global__ __launch_bounds__(256) void build_wpack(const float* __restrict__ Whh,
                                                   const float* __restrict__ Wih,
                                                   unsigned short* __restrict__ wpack) {
    int idx = blockIdx.x * 256 + threadIdx.x;      // 0..196607, each = 8 elems
    int g = idx / 96, cc = idx % 96, k = cc * 8;
    const float* src = (k < H_) ? (Whh + (size_t)g * H_ + k)
                                : (Wih + (size_t)g * D_ + (k - H_));
    union { unsigned short us[8]; uint4 v; } u;
#pragma unroll
    for (int i = 0; i < 8; ++i) u.us[i] = f2bf(src[i]);
    *(uint4*)(wpack + (size_t)idx * 8) = u.v;
}

// ---- prep: zero h0/h1/c(+aliased flags), build bias ----
__global__ __launch_bounds__(256) void init_misc(const float* __restrict__ bih,
                                                 const float* __restrict__ bhh,
                                                 float* __restrict__ bias,
                                                 unsigned int* __restrict__ zreg,
                                                 unsigned int* __restrict__ flags) {
    int gid = blockIdx.x * 256 + threadIdx.x;      // grid 1024 -> 262144
    zreg[gid] = 0u;                                // h0+h1+c region (1 MB, covers flags)
    if (gid < G_) bias[gid] = bih[gid] + bhh[gid];
    if (gid < 16384) flags[gid] = 0u;
}

// ============ persistent cooperative LSTM, dual-chain interleaved ============
// grid 256: pr = bid&7 (pair of 16-row chains A/B), cg = bid>>3 (16 j-cols).
// Chain A = rows pr*32..+16, chain B = rows pr*32+16..+32 -- independent
// recurrences, phase-shifted by half a step so each chain's exchange latency
// (store drain + flag RT + discovery) hides behind the other chain's compute.
// 512 threads = 8 waves; wave w: gate g = w&3, K-half kh = w>>2 (even/odd ks).
// W fragments: 12 x bf16x8 = 48 VGPR, loaded once. c: 1 reg per chain
// (tid<256). h protocol per chain = r9/r10-proven: relaxed agent stores ->
// drain barrier -> relaxed flag; consumer: relaxed poll -> one acquire load
// (L1+L2 inv) -> plain cached loads.
__global__ __launch_bounds__(512, 2) void lstm_persist(
    const float* __restrict__ x,
    const unsigned short* __restrict__ wpack,
    const float* __restrict__ bias,
    unsigned short* __restrict__ h0,
    unsigned short* __restrict__ h1,
    unsigned int* __restrict__ flags)
{
    __shared__ __align__(16) unsigned char AsA[16 * 1536];  // [16 rows][768 k] bf16, swizzled
    __shared__ __align__(16) unsigned char AsB[16 * 1536];
    __shared__ float Pc[2][4][16][17];                       // [kh][gate][row][j]
    __shared__ unsigned char lds_pad[28 * 1024];             // force 1 block/CU

    const int tid  = threadIdx.x;
    const int lane = tid & 63, w = tid >> 6;
    const int g = w & 3, kh = w >> 2;
    const int pr = blockIdx.x & 7, cg = blockIdx.x >> 3;
    const int r0A = pr * 32, r0B = pr * 32 + 16;

    ((volatile unsigned char*)lds_pad)[tid] = 0;   // keep pad alive

    // ---- W fragments: this wave's gate, even/odd K-slices (12 ks) ----
    bf16x8 bfr[12];
    {
        const unsigned short* wrow = wpack
            + (size_t)(g * H_ + cg * 16 + (lane & 15)) * KT_ + ((lane >> 4) * 8);
#pragma unroll
        for (int i = 0; i < 12; ++i) bfr[i] = *(const bf16x8*)(wrow + (2 * i + kh) * 32);
    }

    // ---- epilogue constants (valid for tid<256) ----
    const int erow = (tid >> 4) & 15;
    const int ejj  = tid & 15;
    const float bI = bias[0 * H_ + cg * 16 + ejj];
    const float bF = bias[1 * H_ + cg * 16 + ejj];
    const float bG = bias[2 * H_ + cg * 16 + ejj];
    const float bO = bias[3 * H_ + cg * 16 + ejj];
    float cA = 0.f, cB = 0.f;

    const int arow = lane & 15;
    const int koff = (lane >> 4) * 16;
    const int asw  = (arow & 7) << 4;

    // ---- x prefetch mapping: 16 rows x 256 d per chain, 8 floats/thread ----
    const int xrow = tid >> 5;             // 0..15
    const int xd0  = (tid & 31) * 8;
    const int xsw  = (xrow & 7) << 4;
    const int xkb  = 1024 + xd0 * 2;
    const float* xbA = x + (size_t)(r0A + xrow) * T_ * D_ + xd0;
    const float* xbB = x + (size_t)(r0B + xrow) * T_ * D_ + xd0;

#define STAGE_X(AS, v0, v1) do { \
        union { unsigned short us_[8]; uint4 vv; } u_; \
        u_.us_[0] = f2bf((v0).x); u_.us_[1] = f2bf((v0).y); \
        u_.us_[2] = f2bf((v0).z); u_.us_[3] = f2bf((v0).w); \
        u_.us_[4] = f2bf((v1).x); u_.us_[5] = f2bf((v1).y); \
        u_.us_[6] = f2bf((v1).z); u_.us_[7] = f2bf((v1).w); \
        *(uint4*)((AS) + ((xrow * 1536 + xkb) ^ xsw)) = u_.vv; } while (0)

    float4 ra0, ra1, rb0, rb1;
    // prologue: stage xA(0); regB = xB(0); regA = xA(1)
    {
        float4 t0 = *(const float4*)(xbA);
        float4 t1 = *(const float4*)(xbA + 4);
        STAGE_X(AsA, t0, t1);
    }
    rb0 = *(const float4*)(xbB);      rb1 = *(const float4*)(xbB + 4);
    ra0 = *(const float4*)(xbA + D_); ra1 = *(const float4*)(xbA + D_ + 4);
    __syncthreads();

    unsigned int* myflagA = flags + (size_t)((2 * pr)     * 32 + cg) * 32;
    unsigned int* myflagB = flags + (size_t)((2 * pr + 1) * 32 + cg) * 32;
    unsigned int* pollA   = flags + (size_t)((2 * pr)     * 32 + (lane & 31)) * 32;
    unsigned int* pollB   = flags + (size_t)((2 * pr + 1) * 32 + (lane & 31)) * 32;

    for (int t = 0; t < T_; ++t) {
        const unsigned short* hin  = (t & 1) ? h1 : h0;
        unsigned short*       hout = (t & 1) ? h0 : h1;

        // ================= chain A half =================
        f32x4 acc = {0.f, 0.f, 0.f, 0.f};
#pragma unroll
        for (int i = 8; i < 12; ++i) {       // x-part (ks 16..23, this kh's half)
            int ks = 2 * i + kh;
            bf16x8 av = *(const bf16x8*)(AsA + ((arow * 1536 + ks * 64 + koff) ^ asw));
            acc = __builtin_amdgcn_mfma_f32_16x16x32_bf16(av, bfr[i], acc, 0, 0, 0);
        }
        if (w == 0 && t > 0) {               // flags published a half-step ago
            while (true) {
                unsigned int f = __hip_atomic_load(pollA, __ATOMIC_RELAXED,
                                                   __HIP_MEMORY_SCOPE_AGENT);
                if (__all((int)(f >= (unsigned)t))) break;
                __builtin_amdgcn_s_sleep(1);
            }
            (void)__hip_atomic_load(myflagA, __ATOMIC_ACQUIRE, __HIP_MEMORY_SCOPE_AGENT);
        }
        __syncthreads();
        {   // load hA (16KB cached) ; stage xB(t) ; prefetch xB(t+1) ; write AsA.h
            int c0 = tid, c1 = 512 + tid;
            int row0 = c0 >> 6, off0 = c0 & 63;
            int row1 = c1 >> 6, off1 = c1 & 63;
            uint4 hv0 = *(const uint4*)(hin + (size_t)(r0A + row0) * H_ + off0 * 8);
            uint4 hv1 = *(const uint4*)(hin + (size_t)(r0A + row1) * H_ + off1 * 8);
            STAGE_X(AsB, rb0, rb1);
            int tn = (t + 1 < T_) ? (t + 1) : (T_ - 1);
            rb0 = *(const float4*)(xbB + (size_t)tn * D_);
            rb1 = *(const float4*)(xbB + (size_t)tn * D_ + 4);
            *(uint4*)(AsA + ((row0 * 1536 + off0 * 16) ^ ((row0 & 7) << 4))) = hv0;
            *(uint4*)(AsA + ((row1 * 1536 + off1 * 16) ^ ((row1 & 7) << 4))) = hv1;
        }
        __syncthreads();
#pragma unroll
        for (int i = 0; i < 8; ++i) {        // h-part (ks 0..15, this kh's half)
            int ks = 2 * i + kh;
            bf16x8 av = *(const bf16x8*)(AsA + ((arow * 1536 + ks * 64 + koff) ^ asw));
            acc = __builtin_amdgcn_mfma_f32_16x16x32_bf16(av, bfr[i], acc, 0, 0, 0);
        }
#pragma unroll
        for (int reg = 0; reg < 4; ++reg)
            Pc[kh][g][(lane >> 4) * 4 + reg][lane & 15] = acc[reg];
        __syncthreads();
        if (tid < 256) {
            float gi = Pc[0][0][erow][ejj] + Pc[1][0][erow][ejj] + bI;
            float gf = Pc[0][1][erow][ejj] + Pc[1][1][erow][ejj] + bF;
            float gg = Pc[0][2][erow][ejj] + Pc[1][2][erow][ejj] + bG;
            float go = Pc[0][3][erow][ejj] + Pc[1][3][erow][ejj] + bO;
            float I = sigm(gi), F = sigm(gf), Gv = tanh_(gg), O = sigm(go);
            cA = F * cA + I * Gv;
            __hip_atomic_store(hout + (size_t)(r0A + erow) * H_ + cg * 16 + ejj,
                               f2bf(O * tanh_(cA)), __ATOMIC_RELAXED,
                               __HIP_MEMORY_SCOPE_AGENT);
        }
        __syncthreads();   // drain hA stores
        if (tid == 0)
            __hip_atomic_store(myflagA, (unsigned)(t + 1), __ATOMIC_RELAXED,
                               __HIP_MEMORY_SCOPE_AGENT);

        // ================= chain B half =================
        acc = (f32x4){0.f, 0.f, 0.f, 0.f};
#pragma unroll
        for (int i = 8; i < 12; ++i) {
            int ks = 2 * i + kh;
            bf16x8 av = *(const bf16x8*)(AsB + ((arow * 1536 + ks * 64 + koff) ^ asw));
            acc = __builtin_amdgcn_mfma_f32_16x16x32_bf16(av, bfr[i], acc, 0, 0, 0);
        }
        if (w == 0 && t > 0) {
            while (true) {
                unsigned int f = __hip_atomic_load(pollB, __ATOMIC_RELAXED,
                                                   __HIP_MEMORY_SCOPE_AGENT);
                if (__all((int)(f >= (unsigned)t))) break;
                __builtin_amdgcn_s_sleep(1);
            }
            (void)__hip_atomic_load(myflagB, __ATOMIC_ACQUIRE, __HIP_MEMORY_SCOPE_AGENT);
        }
        __syncthreads();
        {   // load hB ; stage xA(t+1) ; prefetch xA(t+2) ; write AsB.h
            int c0 = tid, c1 = 512 + tid;
            int row0 = c0 >> 6, off0 = c0 & 63;
            int row1 = c1 >> 6, off1 = c1 & 63;
            uint4 hv0 = *(const uint4*)(hin + (size_t)(r0B + row0) * H_ + off0 * 8);
            uint4 hv1 = *(const uint4*)(hin + (size_t)(r0B + row1) * H_ + off1 * 8);
            STAGE_X(AsA, ra0, ra1);
            int tn = (t + 2 < T_) ? (t + 2) : (T_ - 1);
            ra0 = *(const float4*)(xbA + (size_t)tn * D_);
            ra1 = *(const float4*)(xbA + (size_t)tn * D_ + 4);
            *(uint4*)(AsB + ((row0 * 1536 + off0 * 16) ^ ((row0 & 7) << 4))) = hv0;
            *(uint4*)(AsB + ((row1 * 1536 + off1 * 16) ^ ((row1 & 7) << 4))) = hv1;
        }
        __syncthreads();
#pragma unroll
        for (int i = 0; i < 8; ++i) {
            int ks = 2 * i + kh;
            bf16x8 av = *(const bf16x8*)(AsB + ((arow * 1536 + ks * 64 + koff) ^ asw));
            acc = __builtin_amdgcn_mfma_f32_16x16x32_bf16(av, bfr[i], acc, 0, 0, 0);
        }
#pragma unroll
        for (int reg = 0; reg < 4; ++reg)
            Pc[kh][g][(lane >> 4) * 4 + reg][lane & 15] = acc[reg];
        __syncthreads();
        if (tid < 256) {
            float gi = Pc[0][0][erow][ejj] + Pc[1][0][erow][ejj] + bI;
            float gf = Pc[0][1][erow][ejj] + Pc[1][1][erow][ejj] + bF;
            float gg = Pc[0][2][erow][ejj] + Pc[1][2][erow][ejj] + bG;
            float go = Pc[0][3][erow][ejj] + Pc[1][3][erow][ejj] + bO;
            float I = sigm(gi), F = sigm(gf), Gv = tanh_(gg), O = sigm(go);
            cB = F * cB + I * Gv;
            __hip_atomic_store(hout + (size_t)(r0B + erow) * H_ + cg * 16 + ejj,
                               f2bf(O * tanh_(cB)), __ATOMIC_RELAXED,
                               __HIP_MEMORY_SCOPE_AGENT);
        }
        __syncthreads();   // drain hB stores
        if (tid == 0)
            __hip_atomic_store(myflagB, (unsigned)(t + 1), __ATOMIC_RELAXED,
                               __HIP_MEMORY_SCOPE_AGENT);
    }
#undef STAGE_X
}

// ============ fallback per-step kernel (round-1, known passing) ============
__global__ __launch_bounds__(256) void lstm_step(const float* __restrict__ x,
                                                 const unsigned short* __restrict__ wpack,
                                                 const float* __restrict__ bias,
                                                 const unsigned short* __restrict__ hin,
                                                 unsigned short* __restrict__ hout,
                                                 float* __restrict__ cbuf,
                                                 int t) {
    __shared__ __align__(16) unsigned char As[64 * 1536];
    __shared__ __align__(16) unsigned char Ws[128 * 256];

    const int tid = threadIdx.x;
    const int w = tid >> 6, lane = tid & 63;
    const int r0 = blockIdx.x * 64;
    const int j0 = blockIdx.y * 32;

#pragma unroll
    for (int p = 0; p < 16; ++p) {
        int idx = p * 256 + tid;
        int row = idx >> 6, seg = idx & 63;
        uint4 v = *(const uint4*)(hin + (size_t)(r0 + row) * H_ + seg * 8);
        *(uint4*)(As + (((row * 1536) + seg * 16) ^ ((row & 7) << 4))) = v;
    }
#pragma unroll
    for (int p = 0; p < 8; ++p) {
        int idx = p * 256 + tid;
        int row = idx >> 5, seg = idx & 31;
        const float* sp = x + ((size_t)(r0 + row) * T_ + t) * D_ + seg * 8;
        float4 a = *(const float4*)sp;
        float4 b = *(const float4*)(sp + 4);
        union { unsigned short us[8]; uint4 v; } u;
        u.us[0] = f2bf(a.x); u.us[1] = f2bf(a.y); u.us[2] = f2bf(a.z); u.us[3] = f2bf(a.w);
        u.us[4] = f2bf(b.x); u.us[5] = f2bf(b.y); u.us[6] = f2bf(b.z); u.us[7] = f2bf(b.w);
        *(uint4*)(As + (((row * 1536) + 1024 + seg * 16) ^ ((row & 7) << 4))) = u.v;
    }
    __syncthreads();

    f32x4 acc[8];
#pragma unroll
    for (int i = 0; i < 8; ++i) acc[i] = (f32x4){0.f, 0.f, 0.f, 0.f};

    for (int kc = 0; kc < 6; ++kc) {
#pragma unroll
        for (int p = 0; p < 8; ++p) {
            int idx = p * 256 + tid;
            int n = idx >> 4, seg = idx & 15;
            int g = n >> 5, jj = n & 31;
            uint4 v = *(const uint4*)(wpack + (size_t)(g * H_ + j0 + jj) * KT_ + kc * 128 + seg * 8);
            *(uint4*)(Ws + (((n * 256) + seg * 16) ^ ((n & 7) << 4))) = v;
        }
        __syncthreads();
#pragma unroll
        for (int ks = 0; ks < 4; ++ks) {
            int row = w * 16 + (lane & 15);
            int kb = (kc * 128 + ks * 32 + ((lane >> 4) * 8)) * 2;
            bf16x8 av = *(const bf16x8*)(As + ((row * 1536 + kb) ^ ((row & 7) << 4)));
            int kwb = (ks * 32 + ((lane >> 4) * 8)) * 2;
#pragma unroll
            for (int nt = 0; nt < 8; ++nt) {
                int n = (nt >> 1) * 32 + (nt & 1) * 16 + (lane & 15);
                bf16x8 bv = *(const bf16x8*)(Ws + ((n * 256 + kwb) ^ ((n & 7) << 4)));
                acc[nt] = __builtin_amdgcn_mfma_f32_16x16x32_bf16(av, bv, acc[nt], 0, 0, 0);
            }
        }
        __syncthreads();
    }

#pragma unroll
    for (int jt = 0; jt < 2; ++jt) {
        int jc = j0 + jt * 16 + (lane & 15);
        float bi = bias[jc], bf = bias[H_ + jc], bg = bias[2 * H_ + jc], bo = bias[3 * H_ + jc];
        f32x4 ai = acc[0 * 2 + jt];
        f32x4 af = acc[1 * 2 + jt];
        f32x4 ag = acc[2 * 2 + jt];
        f32x4 ao = acc[3 * 2 + jt];
#pragma unroll
        for (int reg = 0; reg < 4; ++reg) {
            int rb = r0 + w * 16 + ((lane >> 4) * 4) + reg;
            float I = sigm(ai[reg] + bi);
            float F = sigm(af[reg] + bf);
            float Gv = tanh_(ag[reg] + bg);
            float O = sigm(ao[reg] + bo);
            size_t ci = (size_t)rb * H_ + jc;
            float cn = F * cbuf[ci] + I * Gv;
            cbuf[ci] = cn;
            hout[ci] = f2bf(O * tanh_(cn));
        }
    }
}

// ---- final: out = sigmoid(h @ W_out^T + b_out), [256,2] ----
__global__ __launch_bounds__(256) void classify(const unsigned short* __restrict__ hbuf,
                                                const float* __restrict__ Wout,
                                                const float* __restrict__ bout,
                                                float* __restrict__ out) {
    int r = threadIdx.x;
    float a0 = 0.f, a1 = 0.f;
    for (int kk = 0; kk < H_ / 8; ++kk) {
        union { unsigned short us[8]; uint4 v; } u;
        u.v = *(const uint4*)(hbuf + (size_t)r * H_ + kk * 8);
#pragma unroll
        for (int i = 0; i < 8; ++i) {
            float hf = bf2f(u.us[i]);
            int k = kk * 8 + i;
            a0 += hf * Wout[k];
            a1 += hf * Wout[H_ + k];
        }
    }
    out[r * 2 + 0] = sigm(a0 + bout[0]);
    out[r * 2 + 1] = sigm(a1 + bout[1]);
}

extern "C" void kernel_launch(void* const* d_in, const int* in_sizes, int n_in,
                              void* d_out, int out_size, void* d_ws, size_t ws_size,
                              hipStream_t stream) {
    const float* x    = (const float*)d_in[0];
    const float* Wih  = (const float*)d_in[1];
    const float* Whh  = (const float*)d_in[2];
    const float* bih  = (const float*)d_in[3];
    const float* bhh  = (const float*)d_in[4];
    const float* Wout = (const float*)d_in[5];
    const float* bout = (const float*)d_in[6];
    float* out = (float*)d_out;
    char* ws = (char*)d_ws;

    unsigned short* wpack = (unsigned short*)(ws + WPACK_OFF);
    float*          bias  = (float*)(ws + BIAS_OFF);
    unsigned short* h0    = (unsigned short*)(ws + H0_OFF);
    unsigned short* h1    = (unsigned short*)(ws + H1_OFF);
    float*          cbuf  = (float*)(ws + C_OFF);
    unsigned int*   flags = (unsigned int*)(ws + FLAG_OFF);   // aliases cbuf (exclusive paths)

    build_wpack<<<768, 256, 0, stream>>>(Whh, Wih, wpack);
    init_misc<<<1024, 256, 0, stream>>>(bih, bhh, bias, (unsigned int*)(ws + H0_OFF), flags);

    // persistent cooperative kernel; fall back to per-step launches if rejected
    const float* xa = x; const unsigned short* wa = wpack; const float* ba = bias;
    unsigned short* h0a = h0; unsigned short* h1a = h1; unsigned int* fa = flags;
    void* args[] = { (void*)&xa, (void*)&wa, (void*)&ba, (void*)&h0a, (void*)&h1a, (void*)&fa };
    hipError_t e = hipLaunchCooperativeKernel((const void*)lstm_persist,
                                              dim3(256), dim3(512), args, 0, stream);
    if (e != hipSuccess) {
        for (int t = 0; t < T_; ++t) {
            const unsigned short* hin = (t & 1) ? h1 : h0;
            unsigned short*      hout = (t & 1) ? h0 : h1;
            lstm_step<<<dim3(4, 16), 256, 0, stream>>>(x, wpack, bias, hin, hout, cbuf, t);
        }
    }
    classify<<<1, 256, 0, stream>>>(h0, Wout, bout, out);
}

// Round 12
// 5379.100 us; speedup vs baseline: 1.2481x; 1.2481x over previous
//
#include <hip/hip_runtime.h>
#include <hip/hip_bf16.h>

#define B_  256
#define T_  1024
#define D_  256
#define H_  512
#define G_  2048   // 4*H
#define KT_ 768    // H + D

// ws layout (bytes)
#define WPACK_OFF 0                        // 2048*768*2 = 3145728
#define BIAS_OFF  3145728                  // 2048*4     = 8192
#define H0_OFF    (BIAS_OFF + 8192)        // 256*512*2  = 262144
#define H1_OFF    (H0_OFF + 262144)
#define C_OFF     (H1_OFF + 262144)        // 512KB: fallback cbuf
#define FLAG_OFF  C_OFF                    // flags alias cbuf (paths exclusive):
                                           // 512 flags x 32 uints = 64KB

typedef __attribute__((ext_vector_type(8))) short bf16x8;
typedef __attribute__((ext_vector_type(4))) float f32x4;

__device__ __forceinline__ unsigned short f2bf(float f) {
    unsigned int u = __float_as_uint(f);
    u = (u + 0x7fffu + ((u >> 16) & 1u)) >> 16;   // RNE
    return (unsigned short)u;
}
__device__ __forceinline__ float bf2f(unsigned short s) {
    return __uint_as_float(((unsigned int)s) << 16);
}
__device__ __forceinline__ float sigm(float v) { return 1.0f / (1.0f + __expf(-v)); }
__device__ __forceinline__ float tanh_(float v) { return 2.0f / (1.0f + __expf(-2.0f * v)) - 1.0f; }

// ---- prep: pack [W_hh | W_ih] rows into bf16 Wpack[2048][768] ----
__global__ __launch_bounds__(256) void build_wpack(const float* __restrict__ Whh,
                                                   const float* __restrict__ Wih,
                                                   unsigned short* __restrict__ wpack) {
    int idx = blockIdx.x * 256 + threadIdx.x;      // 0..196607, each = 8 elems
    int g = idx / 96, cc = idx % 96, k = cc * 8;
    const float* src = (k < H_) ? (Whh + (size_t)g * H_ + k)
                                : (Wih + (size_t)g * D_ + (k - H_));
    union { unsigned short us[8]; uint4 v; } u;
#pragma unroll
    for (int i = 0; i < 8; ++i) u.us[i] = f2bf(src[i]);
    *(uint4*)(wpack + (size_t)idx * 8) = u.v;
}

// ---- prep: zero h0/h1/c(+aliased flags), build bias ----
__global__ __launch_bounds__(256) void init_misc(const float* __restrict__ bih,
                                                 const float* __restrict__ bhh,
                                                 float* __restrict__ bias,
                                                 unsigned int* __restrict__ zreg,
                                                 unsigned int* __restrict__ flags) {
    int gid = blockIdx.x * 256 + threadIdx.x;      // grid 1024 -> 262144
    zreg[gid] = 0u;                                // h0+h1+c region (1 MB, covers flags)
    if (gid < G_) bias[gid] = bih[gid] + bhh[gid];
    if (gid < 16384) flags[gid] = 0u;
}

// ============ persistent cooperative LSTM, 2 blocks/CU ============
// grid 512: rg = bid&15 (rowgroup, 16 batch rows), cg = bid>>4 (16 j-cols).
// 256 threads = 4 waves; wave w = gate g. Per wave: 16 rows x 16 j over
// K=768 = 24 MFMA/step (even/odd-ks dual accumulators for ILP).
// Rowgroup chains are fully independent end-to-end, so the 2 co-resident
// blocks per CU drift in phase: one block's poll/LLC-load stall hides under
// the other's MFMA/VALU (hardware co-scheduling, no barrier coupling).
// W fragments: 24 x bf16x8 = 96 VGPR, loaded once. c: 1 reg/thread.
// h protocol (r9/r10-proven): relaxed agent stores -> drain barrier ->
// relaxed flag; consumer: relaxed poll -> one acquire load (L1+L2 inv) ->
// plain cached loads.
__global__ __launch_bounds__(256, 2) void lstm_persist(
    const float* __restrict__ x,
    const unsigned short* __restrict__ wpack,
    const float* __restrict__ bias,
    unsigned short* __restrict__ h0,
    unsigned short* __restrict__ h1,
    unsigned int* __restrict__ flags)
{
    __shared__ __align__(16) unsigned char As[16 * 1536];   // [16 rows][768 k] bf16, swizzled
    __shared__ float Pc[4][16][17];                          // [gate][row][j]

    const int tid  = threadIdx.x;
    const int lane = tid & 63, w = tid >> 6;
    const int g = w;                                         // wave = gate
    const int rg = blockIdx.x & 15, cg = blockIdx.x >> 4;
    const int r0 = rg * 16;

    // ---- load this wave's W fragments into registers (once) ----
    bf16x8 bfr[24];
    {
        const unsigned short* wrow = wpack
            + (size_t)(g * H_ + cg * 16 + (lane & 15)) * KT_ + ((lane >> 4) * 8);
#pragma unroll
        for (int ks = 0; ks < 24; ++ks) bfr[ks] = *(const bf16x8*)(wrow + ks * 32);
    }

    // ---- per-thread epilogue constants (16 rows x 16 j = 256 threads) ----
    const int erow = tid >> 4;        // 0..15
    const int ejj  = tid & 15;        // 0..15
    const float bI = bias[0 * H_ + cg * 16 + ejj];
    const float bF = bias[1 * H_ + cg * 16 + ejj];
    const float bG = bias[2 * H_ + cg * 16 + ejj];
    const float bO = bias[3 * H_ + cg * 16 + ejj];
    float c_reg = 0.f;

    const int arow = lane & 15;
    const int koff = (lane >> 4) * 16;     // byte offset within 64B k-step
    const int asw  = (arow & 7) << 4;

    // ---- x prefetch (cached): 16 floats/thread (16 rows x 256 d) ----
    const int xrow = tid >> 4;             // 0..15
    const int xd0  = (tid & 15) * 16;      // float index within row
    const float* xbase = x + (size_t)(r0 + xrow) * T_ * D_ + xd0;
    float4 pa = *(const float4*)(xbase + 0);
    float4 pb = *(const float4*)(xbase + 4);
    float4 pc2 = *(const float4*)(xbase + 8);
    float4 pd = *(const float4*)(xbase + 12);

    unsigned int* myflag   = flags + (size_t)(rg * 32 + cg) * 32;
    unsigned int* pollflag = flags + (size_t)(rg * 32 + (lane & 31)) * 32;

    for (int t = 0; t < T_; ++t) {
        const unsigned short* hin = (t & 1) ? h1 : h0;
        unsigned short*      hout = (t & 1) ? h0 : h1;

        // A: stage x(t) from prefetched regs -> As.x (k 512..767); prefetch x(t+1)
        {
            union { unsigned short us[8]; uint4 v; } u0, u1;
            u0.us[0] = f2bf(pa.x);  u0.us[1] = f2bf(pa.y);  u0.us[2] = f2bf(pa.z);  u0.us[3] = f2bf(pa.w);
            u0.us[4] = f2bf(pb.x);  u0.us[5] = f2bf(pb.y);  u0.us[6] = f2bf(pb.z);  u0.us[7] = f2bf(pb.w);
            u1.us[0] = f2bf(pc2.x); u1.us[1] = f2bf(pc2.y); u1.us[2] = f2bf(pc2.z); u1.us[3] = f2bf(pc2.w);
            u1.us[4] = f2bf(pd.x);  u1.us[5] = f2bf(pd.y);  u1.us[6] = f2bf(pd.z);  u1.us[7] = f2bf(pd.w);
            int kb = 1024 + xd0 * 2;
            int xsw = (xrow & 7) << 4;
            *(uint4*)(As + ((xrow * 1536 + kb) ^ xsw))      = u0.v;
            *(uint4*)(As + ((xrow * 1536 + kb + 16) ^ xsw)) = u1.v;
        }
        if (t + 1 < T_) {
            const float* sp = xbase + (size_t)(t + 1) * D_;
            pa = *(const float4*)(sp + 0);
            pb = *(const float4*)(sp + 4);
            pc2 = *(const float4*)(sp + 8);
            pd = *(const float4*)(sp + 12);
        }
        __syncthreads();

        // B1: first half of x-part MFMAs (ks 16..19) -- hides poll wait
        f32x4 acc0 = {0.f, 0.f, 0.f, 0.f}, acc1 = {0.f, 0.f, 0.f, 0.f};
#pragma unroll
        for (int ks = 16; ks < 20; ks += 2) {
            bf16x8 av0 = *(const bf16x8*)(As + ((arow * 1536 + ks * 64 + koff) ^ asw));
            bf16x8 av1 = *(const bf16x8*)(As + ((arow * 1536 + (ks + 1) * 64 + koff) ^ asw));
            acc0 = __builtin_amdgcn_mfma_f32_16x16x32_bf16(av0, bfr[ks], acc0, 0, 0, 0);
            acc1 = __builtin_amdgcn_mfma_f32_16x16x32_bf16(av1, bfr[ks + 1], acc1, 0, 0, 0);
        }

        // C: wave 0 polls the 32 rowgroup flags (relaxed), then ONE acquire
        //    load -> L1+L2 invalidate so phase D can use cached loads.
        if (w == 0 && t > 0) {
            while (true) {
                unsigned int f = __hip_atomic_load(pollflag, __ATOMIC_RELAXED,
                                                   __HIP_MEMORY_SCOPE_AGENT);
                if (__all((int)(f >= (unsigned)t))) break;
                __builtin_amdgcn_s_sleep(1);
            }
            (void)__hip_atomic_load(myflag, __ATOMIC_ACQUIRE, __HIP_MEMORY_SCOPE_AGENT);
        }
        __syncthreads();

        // D: issue cached 16B h loads (4/thread, 16KB) into regs; overlap the
        //    remaining x-part MFMAs (ks 20..23); then stage to As.h.
        {
            uint4 hv[4];
#pragma unroll
            for (int p = 0; p < 4; ++p) {
                int c = p * 256 + tid;            // 0..1023 chunks of 16B
                int row = c >> 6, off = c & 63;
                hv[p] = *(const uint4*)(hin + (size_t)(r0 + row) * H_ + off * 8);
            }
#pragma unroll
            for (int ks = 20; ks < 24; ks += 2) {
                bf16x8 av0 = *(const bf16x8*)(As + ((arow * 1536 + ks * 64 + koff) ^ asw));
                bf16x8 av1 = *(const bf16x8*)(As + ((arow * 1536 + (ks + 1) * 64 + koff) ^ asw));
                acc0 = __builtin_amdgcn_mfma_f32_16x16x32_bf16(av0, bfr[ks], acc0, 0, 0, 0);
                acc1 = __builtin_amdgcn_mfma_f32_16x16x32_bf16(av1, bfr[ks + 1], acc1, 0, 0, 0);
            }
#pragma unroll
            for (int p = 0; p < 4; ++p) {
                int c = p * 256 + tid;
                int row = c >> 6, off = c & 63;
                *(uint4*)(As + ((row * 1536 + off * 16) ^ ((row & 7) << 4))) = hv[p];
            }
        }
        __syncthreads();

        // E: h-part MFMAs (ks 0..15)
#pragma unroll
        for (int ks = 0; ks < 16; ks += 2) {
            bf16x8 av0 = *(const bf16x8*)(As + ((arow * 1536 + ks * 64 + koff) ^ asw));
            bf16x8 av1 = *(const bf16x8*)(As + ((arow * 1536 + (ks + 1) * 64 + koff) ^ asw));
            acc0 = __builtin_amdgcn_mfma_f32_16x16x32_bf16(av0, bfr[ks], acc0, 0, 0, 0);
            acc1 = __builtin_amdgcn_mfma_f32_16x16x32_bf16(av1, bfr[ks + 1], acc1, 0, 0, 0);
        }
        // F: dump gate tile (C layout: col=lane&15, row=(lane>>4)*4+reg)
#pragma unroll
        for (int reg = 0; reg < 4; ++reg) {
            int crow = ((lane >> 4) * 4) + reg;
            Pc[g][crow][lane & 15] = acc0[reg] + acc1[reg];
        }
        __syncthreads();

        // G: cell update; thread owns (erow, ejj); c stays in register;
        //    direct 2B coherent h store (coalesces to 32B segments).
        {
            float gi = Pc[0][erow][ejj] + bI;
            float gf = Pc[1][erow][ejj] + bF;
            float gg = Pc[2][erow][ejj] + bG;
            float go = Pc[3][erow][ejj] + bO;
            float I = sigm(gi), F = sigm(gf), Gv = tanh_(gg), O = sigm(go);
            c_reg = F * c_reg + I * Gv;
            unsigned short hv16 = f2bf(O * tanh_(c_reg));
            __hip_atomic_store(hout + (size_t)(r0 + erow) * H_ + cg * 16 + ejj,
                               hv16, __ATOMIC_RELAXED, __HIP_MEMORY_SCOPE_AGENT);
        }
        __syncthreads();   // all threads' h stores drained before flag
        if (tid == 0)
            __hip_atomic_store(myflag, (unsigned)(t + 1), __ATOMIC_RELAXED,
                               __HIP_MEMORY_SCOPE_AGENT);
    }
}

// ============ fallback per-step kernel (round-1, known passing) ============
__global__ __launch_bounds__(256) void lstm_step(const float* __restrict__ x,
                                                 const unsigned short* __restrict__ wpack,
                                                 const float* __restrict__ bias,
                                                 const unsigned short* __restrict__ hin,
                                                 unsigned short* __restrict__ hout,
                                                 float* __restrict__ cbuf,
                                                 int t) {
    __shared__ __align__(16) unsigned char As[64 * 1536];
    __shared__ __align__(16) unsigned char Ws[128 * 256];

    const int tid = threadIdx.x;
    const int w = tid >> 6, lane = tid & 63;
    const int r0 = blockIdx.x * 64;
    const int j0 = blockIdx.y * 32;

#pragma unroll
    for (int p = 0; p < 16; ++p) {
        int idx = p * 256 + tid;
        int row = idx >> 6, seg = idx & 63;
        uint4 v = *(const uint4*)(hin + (size_t)(r0 + row) * H_ + seg * 8);
        *(uint4*)(As + (((row * 1536) + seg * 16) ^ ((row & 7) << 4))) = v;
    }
#pragma unroll
    for (int p = 0; p < 8; ++p) {
        int idx = p * 256 + tid;
        int row = idx >> 5, seg = idx & 31;
        const float* sp = x + ((size_t)(r0 + row) * T_ + t) * D_ + seg * 8;
        float4 a = *(const float4*)sp;
        float4 b = *(const float4*)(sp + 4);
        union { unsigned short us[8]; uint4 v; } u;
        u.us[0] = f2bf(a.x); u.us[1] = f2bf(a.y); u.us[2] = f2bf(a.z); u.us[3] = f2bf(a.w);
        u.us[4] = f2bf(b.x); u.us[5] = f2bf(b.y); u.us[6] = f2bf(b.z); u.us[7] = f2bf(b.w);
        *(uint4*)(As + (((row * 1536) + 1024 + seg * 16) ^ ((row & 7) << 4))) = u.v;
    }
    __syncthreads();

    f32x4 acc[8];
#pragma unroll
    for (int i = 0; i < 8; ++i) acc[i] = (f32x4){0.f, 0.f, 0.f, 0.f};

    for (int kc = 0; kc < 6; ++kc) {
#pragma unroll
        for (int p = 0; p < 8; ++p) {
            int idx = p * 256 + tid;
            int n = idx >> 4, seg = idx & 15;
            int g = n >> 5, jj = n & 31;
            uint4 v = *(const uint4*)(wpack + (size_t)(g * H_ + j0 + jj) * KT_ + kc * 128 + seg * 8);
            *(uint4*)(Ws + (((n * 256) + seg * 16) ^ ((n & 7) << 4))) = v;
        }
        __syncthreads();
#pragma unroll
        for (int ks = 0; ks < 4; ++ks) {
            int row = w * 16 + (lane & 15);
            int kb = (kc * 128 + ks * 32 + ((lane >> 4) * 8)) * 2;
            bf16x8 av = *(const bf16x8*)(As + ((row * 1536 + kb) ^ ((row & 7) << 4)));
            int kwb = (ks * 32 + ((lane >> 4) * 8)) * 2;
#pragma unroll
            for (int nt = 0; nt < 8; ++nt) {
                int n = (nt >> 1) * 32 + (nt & 1) * 16 + (lane & 15);
                bf16x8 bv = *(const bf16x8*)(Ws + ((n * 256 + kwb) ^ ((n & 7) << 4)));
                acc[nt] = __builtin_amdgcn_mfma_f32_16x16x32_bf16(av, bv, acc[nt], 0, 0, 0);
            }
        }
        __syncthreads();
    }

#pragma unroll
    for (int jt = 0; jt < 2; ++jt) {
        int jc = j0 + jt * 16 + (lane & 15);
        float bi = bias[jc], bf = bias[H_ + jc], bg = bias[2 * H_ + jc], bo = bias[3 * H_ + jc];
        f32x4 ai = acc[0 * 2 + jt];
        f32x4 af = acc[1 * 2 + jt];
        f32x4 ag = acc[2 * 2 + jt];
        f32x4 ao = acc[3 * 2 + jt];
#pragma unroll
        for (int reg = 0; reg < 4; ++reg) {
            int rb = r0 + w * 16 + ((lane >> 4) * 4) + reg;
            float I = sigm(ai[reg] + bi);
            float F = sigm(af[reg] + bf);
            float Gv = tanh_(ag[reg] + bg);
            float O = sigm(ao[reg] + bo);
            size_t ci = (size_t)rb * H_ + jc;
            float cn = F * cbuf[ci] + I * Gv;
            cbuf[ci] = cn;
            hout[ci] = f2bf(O * tanh_(cn));
        }
    }
}

// ---- final: out = sigmoid(h @ W_out^T + b_out), [256,2] ----
__global__ __launch_bounds__(256) void classify(const unsigned short* __restrict__ hbuf,
                                                const float* __restrict__ Wout,
                                                const float* __restrict__ bout,
                                                float* __restrict__ out) {
    int r = threadIdx.x;
    float a0 = 0.f, a1 = 0.f;
    for (int kk = 0; kk < H_ / 8; ++kk) {
        union { unsigned short us[8]; uint4 v; } u;
        u.v = *(const uint4*)(hbuf + (size_t)r * H_ + kk * 8);
#pragma unroll
        for (int i = 0; i < 8; ++i) {
            float hf = bf2f(u.us[i]);
            int k = kk * 8 + i;
            a0 += hf * Wout[k];
            a1 += hf * Wout[H_ + k];
        }
    }
    out[r * 2 + 0] = sigm(a0 + bout[0]);
    out[r * 2 + 1] = sigm(a1 + bout[1]);
}

extern "C" void kernel_launch(void* const* d_in, const int* in_sizes, int n_in,
                              void* d_out, int out_size, void* d_ws, size_t ws_size,
                              hipStream_t stream) {
    const float* x    = (const float*)d_in[0];
    const float* Wih  = (const float*)d_in[1];
    const float* Whh  = (const float*)d_in[2];
    const float* bih  = (const float*)d_in[3];
    const float* bhh  = (const float*)d_in[4];
    const float* Wout = (const float*)d_in[5];
    const float* bout = (const float*)d_in[6];
    float* out = (float*)d_out;
    char* ws = (char*)d_ws;

    unsigned short* wpack = (unsigned short*)(ws + WPACK_OFF);
    float*          bias  = (float*)(ws + BIAS_OFF);
    unsigned short* h0    = (unsigned short*)(ws + H0_OFF);
    unsigned short* h1    = (unsigned short*)(ws + H1_OFF);
    float*          cbuf  = (float*)(ws + C_OFF);
    unsigned int*   flags = (unsigned int*)(ws + FLAG_OFF);   // aliases cbuf (exclusive paths)

    build_wpack<<<768, 256, 0, stream>>>(Whh, Wih, wpack);
    init_misc<<<1024, 256, 0, stream>>>(bih, bhh, bias, (unsigned int*)(ws + H0_OFF), flags);

    // persistent cooperative kernel; fall back to per-step launches if rejected
    const float* xa = x; const unsigned short* wa = wpack; const float* ba = bias;
    unsigned short* h0a = h0; unsigned short* h1a = h1; unsigned int* fa = flags;
    void* args[] = { (void*)&xa, (void*)&wa, (void*)&ba, (void*)&h0a, (void*)&h1a, (void*)&fa };
    hipError_t e = hipLaunchCooperativeKernel((const void*)lstm_persist,
                                              dim3(512), dim3(256), args, 0, stream);
    if (e != hipSuccess) {
        for (int t = 0; t < T_; ++t) {
            const unsigned short* hin = (t & 1) ? h1 : h0;
            unsigned short*      hout = (t & 1) ? h0 : h1;
            lstm_step<<<dim3(4, 16), 256, 0, stream>>>(x, wpack, bias, hin, hout, cbuf, t);
        }
    }
    classify<<<1, 256, 0, stream>>>(h0, Wout, bout, out);
}

// Round 13
// 4061.266 us; speedup vs baseline: 1.6531x; 1.3245x over previous
//
#include <hip/hip_runtime.h>
#include <hip/hip_bf16.h>

#define B_  256
#define T_  1024
#define D_  256
#define H_  512
#define G_  2048   // 4*H
#define KT_ 768    // H + D

// ws layout (bytes)
#define WPACK_OFF 0                        // 2048*768*2 = 3145728
#define BIAS_OFF  3145728                  // 2048*4     = 8192
#define H0_OFF    (BIAS_OFF + 8192)        // 256*512*2  = 262144
#define H1_OFF    (H0_OFF + 262144)
#define C_OFF     (H1_OFF + 262144)        // 512KB: fallback cbuf
#define FLAG_OFF  C_OFF                    // flags alias cbuf (paths exclusive):
                                           // 256 flags x 32 uints = 32KB

typedef __attribute__((ext_vector_type(8))) short bf16x8;
typedef __attribute__((ext_vector_type(4))) float f32x4;

__device__ __forceinline__ unsigned short f2bf(float f) {
    unsigned int u = __float_as_uint(f);
    u = (u + 0x7fffu + ((u >> 16) & 1u)) >> 16;   // RNE
    return (unsigned short)u;
}
__device__ __forceinline__ float bf2f(unsigned short s) {
    return __uint_as_float(((unsigned int)s) << 16);
}
__device__ __forceinline__ float sigm(float v) { return 1.0f / (1.0f + __expf(-v)); }
__device__ __forceinline__ float tanh_(float v) { return 2.0f / (1.0f + __expf(-2.0f * v)) - 1.0f; }

// ---- prep: pack [W_hh | W_ih] rows into bf16 Wpack[2048][768] ----
__global__ __launch_bounds__(256) void build_wpack(const float* __restrict__ Whh,
                                                   const float* __restrict__ Wih,
                                                   unsigned short* __restrict__ wpack) {
    int idx = blockIdx.x * 256 + threadIdx.x;      // 0..196607, each = 8 elems
    int g = idx / 96, cc = idx % 96, k = cc * 8;
    const float* src = (k < H_) ? (Whh + (size_t)g * H_ + k)
                                : (Wih + (size_t)g * D_ + (k - H_));
    union { unsigned short us[8]; uint4 v; } u;
#pragma unroll
    for (int i = 0; i < 8; ++i) u.us[i] = f2bf(src[i]);
    *(uint4*)(wpack + (size_t)idx * 8) = u.v;
}

// ---- prep: zero h0/h1/c(+aliased flags), build bias ----
__global__ __launch_bounds__(256) void init_misc(const float* __restrict__ bih,
                                                 const float* __restrict__ bhh,
                                                 float* __restrict__ bias,
                                                 unsigned int* __restrict__ zreg,
                                                 unsigned int* __restrict__ flags) {
    int gid = blockIdx.x * 256 + threadIdx.x;      // grid 1024 -> 262144
    zreg[gid] = 0u;                                // h0+h1+c region (1 MB, covers flags)
    if (gid < G_) bias[gid] = bih[gid] + bhh[gid];
    if (gid < 16384) flags[gid] = 0u;
}

// ============ persistent cooperative LSTM ============
// grid 256: rg = bid&15 (rowgroup, 16 batch rows), cg = bid>>4 (32 j-cols).
// Sync domain per rowgroup = 16 blocks (half of r10): less skew, 16KB h-load.
// 512 threads = 8 waves; wave w: gate g = w>>1, col-half jt = w&1 (16 j).
// W fragments: 24 x bf16x8 = 96 VGPR, loaded once. c: 1 reg/thread.
// h protocol (r9/r10-proven): relaxed agent stores -> drain -> relaxed flag;
// consumer: relaxed poll -> one acquire load (L1+L2 inv) -> cached loads.
// NEW tail: wave 0 alone stores the 1KB Hs tile, drains ITS OWN vmcnt
// (wave-uniform), publishes flag -- overlapped with waves 1-7 staging x(t+1).
// LDS padded (volatile) so 1 block/CU -> 256 blocks on 256 CUs.
__global__ __launch_bounds__(512, 2) void lstm_persist(
    const float* __restrict__ x,
    const unsigned short* __restrict__ wpack,
    const float* __restrict__ bias,
    unsigned short* __restrict__ h0,
    unsigned short* __restrict__ h1,
    unsigned int* __restrict__ flags)
{
    __shared__ __align__(16) unsigned char As[16 * 1536];   // [16 rows][768 k] bf16, swizzled
    __shared__ float Pc[4][16][33];                          // [gate][row][j], padded
    __shared__ __align__(16) unsigned short Hs[16][32];      // new h tile (bf16)
    __shared__ unsigned char lds_pad[50 * 1024];             // force 1 block/CU

    const int tid  = threadIdx.x;
    const int lane = tid & 63, w = tid >> 6;
    const int g = w >> 1, jt = w & 1;
    const int rg = blockIdx.x & 15, cg = blockIdx.x >> 4;
    const int r0 = rg * 16;

    ((volatile unsigned char*)lds_pad)[tid] = 0;   // keep pad alive

    // ---- load this wave's W fragments into registers (once) ----
    bf16x8 bfr[24];
    {
        const unsigned short* wrow = wpack
            + (size_t)(g * H_ + cg * 32 + jt * 16 + (lane & 15)) * KT_ + ((lane >> 4) * 8);
#pragma unroll
        for (int ks = 0; ks < 24; ++ks) bfr[ks] = *(const bf16x8*)(wrow + ks * 32);
    }

    // ---- per-thread epilogue constants (16 rows x 32 j = 512 threads) ----
    const int erow = tid >> 5;        // 0..15
    const int ejj  = tid & 31;        // 0..31
    const float bI = bias[0 * H_ + cg * 32 + ejj];
    const float bF = bias[1 * H_ + cg * 32 + ejj];
    const float bG = bias[2 * H_ + cg * 32 + ejj];
    const float bO = bias[3 * H_ + cg * 32 + ejj];
    float c_reg = 0.f;

    const int arow = lane & 15;            // A-tile row
    const int koff = (lane >> 4) * 16;     // byte offset within 64B k-step
    const int asw  = (arow & 7) << 4;

    // ---- x staging: waves 1-7 only (448 threads, 512 chunks of 8 floats) ----
    // chunk c: xrow = c>>5 (0..15), seg = c&31; thread tt=tid-64 owns chunk tt
    // and (if tt<64) chunk tt+448.
    const int tt  = tid - 64;
    const int xc0 = tt, xc1 = tt + 448;
    const float* xb0 = nullptr;
    const float* xb1 = nullptr;
    float4 p0a, p0b, p1a, p1b;
    if (tid >= 64) {
        xb0 = x + (size_t)(r0 + (xc0 >> 5)) * T_ * D_ + (xc0 & 31) * 8;
        p0a = *(const float4*)(xb0);
        p0b = *(const float4*)(xb0 + 4);
        if (xc1 < 512) {
            xb1 = x + (size_t)(r0 + (xc1 >> 5)) * T_ * D_ + (xc1 & 31) * 8;
            p1a = *(const float4*)(xb1);
            p1b = *(const float4*)(xb1 + 4);
        }
    }

    unsigned int* myflag   = flags + (size_t)(rg * 16 + cg) * 32;
    unsigned int* pollflag = flags + (size_t)(rg * 16 + (lane & 15)) * 32;

    for (int t = 0; t < T_; ++t) {
        const unsigned short* hin = (t & 1) ? h1 : h0;
        unsigned short*      hout = (t & 1) ? h0 : h1;

        // A: waves 1-7 stage x(t) -> As.x (k 512..767) and prefetch x(t+1).
        //    (wave 0 is finishing the previous step's tail meanwhile.)
        if (tid >= 64) {
            {
                union { unsigned short us[8]; uint4 v; } u;
                u.us[0] = f2bf(p0a.x); u.us[1] = f2bf(p0a.y); u.us[2] = f2bf(p0a.z); u.us[3] = f2bf(p0a.w);
                u.us[4] = f2bf(p0b.x); u.us[5] = f2bf(p0b.y); u.us[6] = f2bf(p0b.z); u.us[7] = f2bf(p0b.w);
                int r = xc0 >> 5, s = xc0 & 31;
                *(uint4*)(As + ((r * 1536 + 1024 + s * 16) ^ ((r & 7) << 4))) = u.v;
            }
            if (xc1 < 512) {
                union { unsigned short us[8]; uint4 v; } u;
                u.us[0] = f2bf(p1a.x); u.us[1] = f2bf(p1a.y); u.us[2] = f2bf(p1a.z); u.us[3] = f2bf(p1a.w);
                u.us[4] = f2bf(p1b.x); u.us[5] = f2bf(p1b.y); u.us[6] = f2bf(p1b.z); u.us[7] = f2bf(p1b.w);
                int r = xc1 >> 5, s = xc1 & 31;
                *(uint4*)(As + ((r * 1536 + 1024 + s * 16) ^ ((r & 7) << 4))) = u.v;
            }
            if (t + 1 < T_) {
                const float* sp = xb0 + (size_t)(t + 1) * D_;
                p0a = *(const float4*)(sp);
                p0b = *(const float4*)(sp + 4);
                if (xc1 < 512) {
                    sp = xb1 + (size_t)(t + 1) * D_;
                    p1a = *(const float4*)(sp);
                    p1b = *(const float4*)(sp + 4);
                }
            }
        }
        __syncthreads();

        // B1: first half of x-part MFMAs (ks 16..19) -- hides poll wait
        f32x4 acc0 = {0.f, 0.f, 0.f, 0.f}, acc1 = {0.f, 0.f, 0.f, 0.f};
#pragma unroll
        for (int ks = 16; ks < 20; ks += 2) {
            bf16x8 av0 = *(const bf16x8*)(As + ((arow * 1536 + ks * 64 + koff) ^ asw));
            bf16x8 av1 = *(const bf16x8*)(As + ((arow * 1536 + (ks + 1) * 64 + koff) ^ asw));
            acc0 = __builtin_amdgcn_mfma_f32_16x16x32_bf16(av0, bfr[ks], acc0, 0, 0, 0);
            acc1 = __builtin_amdgcn_mfma_f32_16x16x32_bf16(av1, bfr[ks + 1], acc1, 0, 0, 0);
        }

        // C: wave 0 polls the 16 rowgroup flags (relaxed), then ONE acquire
        //    load -> L1+L2 invalidate so phase D can use cached loads.
        if (w == 0 && t > 0) {
            while (true) {
                unsigned int f = __hip_atomic_load(pollflag, __ATOMIC_RELAXED,
                                                   __HIP_MEMORY_SCOPE_AGENT);
                if (__all((int)(f >= (unsigned)t))) break;
                __builtin_amdgcn_s_sleep(1);
            }
            (void)__hip_atomic_load(myflag, __ATOMIC_ACQUIRE, __HIP_MEMORY_SCOPE_AGENT);
        }
        __syncthreads();

        // D: issue cached 16B h loads (2/thread, 16KB) into regs; overlap the
        //    remaining x-part MFMAs (ks 20..23); then stage to As.h.
        {
            uint4 hv0, hv1;
            {
                int c = tid;                      // 0..511
                int row = c >> 6, off = c & 63;
                hv0 = *(const uint4*)(hin + (size_t)(r0 + row) * H_ + off * 8);
                c = 512 + tid;
                row = c >> 6; off = c & 63;
                hv1 = *(const uint4*)(hin + (size_t)(r0 + row) * H_ + off * 8);
            }
#pragma unroll
            for (int ks = 20; ks < 24; ks += 2) {
                bf16x8 av0 = *(const bf16x8*)(As + ((arow * 1536 + ks * 64 + koff) ^ asw));
                bf16x8 av1 = *(const bf16x8*)(As + ((arow * 1536 + (ks + 1) * 64 + koff) ^ asw));
                acc0 = __builtin_amdgcn_mfma_f32_16x16x32_bf16(av0, bfr[ks], acc0, 0, 0, 0);
                acc1 = __builtin_amdgcn_mfma_f32_16x16x32_bf16(av1, bfr[ks + 1], acc1, 0, 0, 0);
            }
            {
                int c = tid;
                int row = c >> 6, off = c & 63;
                *(uint4*)(As + ((row * 1536 + off * 16) ^ ((row & 7) << 4))) = hv0;
                c = 512 + tid;
                row = c >> 6; off = c & 63;
                *(uint4*)(As + ((row * 1536 + off * 16) ^ ((row & 7) << 4))) = hv1;
            }
        }
        __syncthreads();

        // E: h-part MFMAs (ks 0..15)
#pragma unroll
        for (int ks = 0; ks < 16; ks += 2) {
            bf16x8 av0 = *(const bf16x8*)(As + ((arow * 1536 + ks * 64 + koff) ^ asw));
            bf16x8 av1 = *(const bf16x8*)(As + ((arow * 1536 + (ks + 1) * 64 + koff) ^ asw));
            acc0 = __builtin_amdgcn_mfma_f32_16x16x32_bf16(av0, bfr[ks], acc0, 0, 0, 0);
            acc1 = __builtin_amdgcn_mfma_f32_16x16x32_bf16(av1, bfr[ks + 1], acc1, 0, 0, 0);
        }
        // F: dump gate tile (C layout: col=lane&15, row=(lane>>4)*4+reg)
#pragma unroll
        for (int reg = 0; reg < 4; ++reg) {
            int crow = ((lane >> 4) * 4) + reg;
            Pc[g][crow][jt * 16 + (lane & 15)] = acc0[reg] + acc1[reg];
        }
        __syncthreads();

        // G: cell update; thread owns (erow, ejj); c stays in register;
        //    write h to Hs (LDS) for the wave-0 tail.
        {
            float gi = Pc[0][erow][ejj] + bI;
            float gf = Pc[1][erow][ejj] + bF;
            float gg = Pc[2][erow][ejj] + bG;
            float go = Pc[3][erow][ejj] + bO;
            float I = sigm(gi), F = sigm(gf), Gv = tanh_(gg), O = sigm(go);
            c_reg = F * c_reg + I * Gv;
            Hs[erow][ejj] = f2bf(O * tanh_(c_reg));
        }
        __syncthreads();

        // H: wave 0 alone stores the 1KB tile (16B/lane as 2x8B relaxed),
        //    drains ITS OWN vmcnt (wave-uniform branch), publishes the flag.
        //    Waves 1-7 run ahead into next-step A (they only touch As.x).
        if (tid < 64) {
            int row = tid >> 2, part = tid & 3;
            const unsigned long long* src = (const unsigned long long*)(&Hs[row][part * 8]);
            unsigned long long v0 = src[0], v1 = src[1];
            unsigned long long* dst = (unsigned long long*)(hout + (size_t)(r0 + row) * H_ + cg * 32 + part * 8);
            __hip_atomic_store(dst,     v0, __ATOMIC_RELAXED, __HIP_MEMORY_SCOPE_AGENT);
            __hip_atomic_store(dst + 1, v1, __ATOMIC_RELAXED, __HIP_MEMORY_SCOPE_AGENT);
            asm volatile("s_waitcnt vmcnt(0)" ::: "memory");
            if (tid == 0)
                __hip_atomic_store(myflag, (unsigned)(t + 1), __ATOMIC_RELAXED,
                                   __HIP_MEMORY_SCOPE_AGENT);
        }
    }
}

// ============ fallback per-step kernel (round-1, known passing) ============
__global__ __launch_bounds__(256) void lstm_step(const float* __restrict__ x,
                                                 const unsigned short* __restrict__ wpack,
                                                 const float* __restrict__ bias,
                                                 const unsigned short* __restrict__ hin,
                                                 unsigned short* __restrict__ hout,
                                                 float* __restrict__ cbuf,
                                                 int t) {
    __shared__ __align__(16) unsigned char As[64 * 1536];
    __shared__ __align__(16) unsigned char Ws[128 * 256];

    const int tid = threadIdx.x;
    const int w = tid >> 6, lane = tid & 63;
    const int r0 = blockIdx.x * 64;
    const int j0 = blockIdx.y * 32;

#pragma unroll
    for (int p = 0; p < 16; ++p) {
        int idx = p * 256 + tid;
        int row = idx >> 6, seg = idx & 63;
        uint4 v = *(const uint4*)(hin + (size_t)(r0 + row) * H_ + seg * 8);
        *(uint4*)(As + (((row * 1536) + seg * 16) ^ ((row & 7) << 4))) = v;
    }
#pragma unroll
    for (int p = 0; p < 8; ++p) {
        int idx = p * 256 + tid;
        int row = idx >> 5, seg = idx & 31;
        const float* sp = x + ((size_t)(r0 + row) * T_ + t) * D_ + seg * 8;
        float4 a = *(const float4*)sp;
        float4 b = *(const float4*)(sp + 4);
        union { unsigned short us[8]; uint4 v; } u;
        u.us[0] = f2bf(a.x); u.us[1] = f2bf(a.y); u.us[2] = f2bf(a.z); u.us[3] = f2bf(a.w);
        u.us[4] = f2bf(b.x); u.us[5] = f2bf(b.y); u.us[6] = f2bf(b.z); u.us[7] = f2bf(b.w);
        *(uint4*)(As + (((row * 1536) + 1024 + seg * 16) ^ ((row & 7) << 4))) = u.v;
    }
    __syncthreads();

    f32x4 acc[8];
#pragma unroll
    for (int i = 0; i < 8; ++i) acc[i] = (f32x4){0.f, 0.f, 0.f, 0.f};

    for (int kc = 0; kc < 6; ++kc) {
#pragma unroll
        for (int p = 0; p < 8; ++p) {
            int idx = p * 256 + tid;
            int n = idx >> 4, seg = idx & 15;
            int g = n >> 5, jj = n & 31;
            uint4 v = *(const uint4*)(wpack + (size_t)(g * H_ + j0 + jj) * KT_ + kc * 128 + seg * 8);
            *(uint4*)(Ws + (((n * 256) + seg * 16) ^ ((n & 7) << 4))) = v;
        }
        __syncthreads();
#pragma unroll
        for (int ks = 0; ks < 4; ++ks) {
            int row = w * 16 + (lane & 15);
            int kb = (kc * 128 + ks * 32 + ((lane >> 4) * 8)) * 2;
            bf16x8 av = *(const bf16x8*)(As + ((row * 1536 + kb) ^ ((row & 7) << 4)));
            int kwb = (ks * 32 + ((lane >> 4) * 8)) * 2;
#pragma unroll
            for (int nt = 0; nt < 8; ++nt) {
                int n = (nt >> 1) * 32 + (nt & 1) * 16 + (lane & 15);
                bf16x8 bv = *(const bf16x8*)(Ws + ((n * 256 + kwb) ^ ((n & 7) << 4)));
                acc[nt] = __builtin_amdgcn_mfma_f32_16x16x32_bf16(av, bv, acc[nt], 0, 0, 0);
            }
        }
        __syncthreads();
    }

#pragma unroll
    for (int jt = 0; jt < 2; ++jt) {
        int jc = j0 + jt * 16 + (lane & 15);
        float bi = bias[jc], bf = bias[H_ + jc], bg = bias[2 * H_ + jc], bo = bias[3 * H_ + jc];
        f32x4 ai = acc[0 * 2 + jt];
        f32x4 af = acc[1 * 2 + jt];
        f32x4 ag = acc[2 * 2 + jt];
        f32x4 ao = acc[3 * 2 + jt];
#pragma unroll
        for (int reg = 0; reg < 4; ++reg) {
            int rb = r0 + w * 16 + ((lane >> 4) * 4) + reg;
            float I = sigm(ai[reg] + bi);
            float F = sigm(af[reg] + bf);
            float Gv = tanh_(ag[reg] + bg);
            float O = sigm(ao[reg] + bo);
            size_t ci = (size_t)rb * H_ + jc;
            float cn = F * cbuf[ci] + I * Gv;
            cbuf[ci] = cn;
            hout[ci] = f2bf(O * tanh_(cn));
        }
    }
}

// ---- final: out = sigmoid(h @ W_out^T + b_out), [256,2] ----
__global__ __launch_bounds__(256) void classify(const unsigned short* __restrict__ hbuf,
                                                const float* __restrict__ Wout,
                                                const float* __restrict__ bout,
                                                float* __restrict__ out) {
    int r = threadIdx.x;
    float a0 = 0.f, a1 = 0.f;
    for (int kk = 0; kk < H_ / 8; ++kk) {
        union { unsigned short us[8]; uint4 v; } u;
        u.v = *(const uint4*)(hbuf + (size_t)r * H_ + kk * 8);
#pragma unroll
        for (int i = 0; i < 8; ++i) {
            float hf = bf2f(u.us[i]);
            int k = kk * 8 + i;
            a0 += hf * Wout[k];
            a1 += hf * Wout[H_ + k];
        }
    }
    out[r * 2 + 0] = sigm(a0 + bout[0]);
    out[r * 2 + 1] = sigm(a1 + bout[1]);
}

extern "C" void kernel_launch(void* const* d_in, const int* in_sizes, int n_in,
                              void* d_out, int out_size, void* d_ws, size_t ws_size,
                              hipStream_t stream) {
    const float* x    = (const float*)d_in[0];
    const float* Wih  = (const float*)d_in[1];
    const float* Whh  = (const float*)d_in[2];
    const float* bih  = (const float*)d_in[3];
    const float* bhh  = (const float*)d_in[4];
    const float* Wout = (const float*)d_in[5];
    const float* bout = (const float*)d_in[6];
    float* out = (float*)d_out;
    char* ws = (char*)d_ws;

    unsigned short* wpack = (unsigned short*)(ws + WPACK_OFF);
    float*          bias  = (float*)(ws + BIAS_OFF);
    unsigned short* h0    = (unsigned short*)(ws + H0_OFF);
    unsigned short* h1    = (unsigned short*)(ws + H1_OFF);
    float*          cbuf  = (float*)(ws + C_OFF);
    unsigned int*   flags = (unsigned int*)(ws + FLAG_OFF);   // aliases cbuf (exclusive paths)

    build_wpack<<<768, 256, 0, stream>>>(Whh, Wih, wpack);
    init_misc<<<1024, 256, 0, stream>>>(bih, bhh, bias, (unsigned int*)(ws + H0_OFF), flags);

    // persistent cooperative kernel; fall back to per-step launches if rejected
    const float* xa = x; const unsigned short* wa = wpack; const float* ba = bias;
    unsigned short* h0a = h0; unsigned short* h1a = h1; unsigned int* fa = flags;
    void* args[] = { (void*)&xa, (void*)&wa, (void*)&ba, (void*)&h0a, (void*)&h1a, (void*)&fa };
    hipError_t e = hipLaunchCooperativeKernel((const void*)lstm_persist,
                                              dim3(256), dim3(512), args, 0, stream);
    if (e != hipSuccess) {
        for (int t = 0; t < T_; ++t) {
            const unsigned short* hin = (t & 1) ? h1 : h0;
            unsigned short*      hout = (t & 1) ? h0 : h1;
            lstm_step<<<dim3(4, 16), 256, 0, stream>>>(x, wpack, bias, hin, hout, cbuf, t);
        }
    }
    classify<<<1, 256, 0, stream>>>(h0, Wout, bout, out);
}